// Round 1
// 227.726 us; speedup vs baseline: 1.0581x; 1.0581x over previous
//
#include <hip/hip_runtime.h>

#define BB 512
#define TT 512
#define NN 64

__device__ __forceinline__ float readlane_f(float v, int lane) {
    return __int_as_float(__builtin_amdgcn_readlane(__float_as_int(v), lane));
}

// Full 64-term dot: s_j = sum_i p[i] * E[i][j], p broadcast via v_readlane
// (in-register, no LDS, no barrier). 4 independent accumulator chains so the
// fma latency (4 cyc) hides under issue (2 cyc/instr, 128 instrs).
__device__ __forceinline__ float dot64(float p, const float4* E) {
    float s0 = readlane_f(p, 0) * E[0].x;
    float s1 = readlane_f(p, 1) * E[0].y;
    float s2 = readlane_f(p, 2) * E[0].z;
    float s3 = readlane_f(p, 3) * E[0].w;
    #pragma unroll
    for (int g = 1; g < 16; ++g) {
        s0 = fmaf(readlane_f(p, 4 * g + 0), E[g].x, s0);
        s1 = fmaf(readlane_f(p, 4 * g + 1), E[g].y, s1);
        s2 = fmaf(readlane_f(p, 4 * g + 2), E[g].z, s2);
        s3 = fmaf(readlane_f(p, 4 * g + 3), E[g].w, s3);
    }
    return (s0 + s1) + (s2 + s3);
}

// One WAVE per batch. Lane j tracks alpha[j] and holds the full E column j
// (64 VGPRs) -> the per-step cross-lane reduction is entirely in-register.
// No __syncthreads in the t-loop at all; the previous 4-wave design paid
// ~700 cyc/step in barrier+LDS lockstep (measured 780 cyc/step vs ~84 cyc
// of VALU issue). Emits double-buffered 16 ahead in named float4 regs.
__global__ __launch_bounds__(64, 1) void crf_kernel(
    const float* __restrict__ inputs,   // B*T*N fp32
    const float* __restrict__ trans,    // N*N fp32
    const int*   __restrict__ tags,     // B*T
    const int*   __restrict__ lens,     // B
    float*       __restrict__ out)      // [0,512) ll, [512,4608) trans copy
{
    const int b = blockIdx.x;
    const int j = threadIdx.x;          // 0..63

    // pass-through output: transition_params (4096 floats over first 64 blocks)
    if (b < 64) out[BB + b * 64 + j] = trans[b * 64 + j];

    const int L    = lens[b];
    const int last = (L - 1) > 0 ? (L - 1) : 0;

    const float* inb  = inputs + (size_t)b * TT * NN;
    const int*   tagb = tags + (size_t)b * TT;

    // ---- sequence score: unary (t < L) + binary (t+1 < L), 64 lanes x 8 ----
    float sc = 0.f;
    #pragma unroll
    for (int k = 0; k < 8; ++k) {
        const int t  = k * 64 + j;
        const int tg = tagb[t];
        if (t < L) sc += inb[t * NN + tg];
        if (t + 1 < L) sc += trans[tg * NN + tagb[t + 1]];   // L<=511 => safe
    }
    #pragma unroll
    for (int x = 32; x >= 1; x >>= 1) sc += __shfl_xor(sc, x, 64);

    // ---- E column j: E[i][j] = exp(trans[i][j]), 64 floats in VGPRs ----
    float4 E[16];
    #pragma unroll
    for (int g = 0; g < 16; ++g) {
        E[g].x = __expf(trans[(4 * g + 0) * NN + j]);
        E[g].y = __expf(trans[(4 * g + 1) * NN + j]);
        E[g].z = __expf(trans[(4 * g + 2) * NN + j]);
        E[g].w = __expf(trans[(4 * g + 3) * NN + j]);
    }

    float alpha = inb[j];   // t = 0

    // emit double-buffer: chunk A computes while chunk B loads, stride 32.
    float4 pA0, pA1, pA2, pA3, pB0, pB1, pB2, pB3;

#define LD(vec, comp, tt) { const int tc_ = (tt) <= last ? (tt) : last; \
                            vec.comp = inb[tc_ * NN + j]; }
#define LOADCHUNK(v0, v1, v2, v3, base) \
    LD(v0, x, (base) + 0)  LD(v0, y, (base) + 1)  LD(v0, z, (base) + 2)  LD(v0, w, (base) + 3)  \
    LD(v1, x, (base) + 4)  LD(v1, y, (base) + 5)  LD(v1, z, (base) + 6)  LD(v1, w, (base) + 7)  \
    LD(v2, x, (base) + 8)  LD(v2, y, (base) + 9)  LD(v2, z, (base) + 10) LD(v2, w, (base) + 11) \
    LD(v3, x, (base) + 12) LD(v3, y, (base) + 13) LD(v3, z, (base) + 14) LD(v3, w, (base) + 15)

#define STEP(tc_, EM) { \
    const float m = readlane_f(alpha, 0); \
    const float p = __expf(alpha - m); \
    const float s = dot64(p, E); \
    if ((tc_) <= last) alpha = ((EM) + m) + __logf(s); \
}

    LOADCHUNK(pA0, pA1, pA2, pA3, 1)

    for (int t0 = 1; t0 <= last; t0 += 32) {
        LOADCHUNK(pB0, pB1, pB2, pB3, t0 + 16)
        STEP(t0 + 0,  pA0.x) STEP(t0 + 1,  pA0.y) STEP(t0 + 2,  pA0.z) STEP(t0 + 3,  pA0.w)
        STEP(t0 + 4,  pA1.x) STEP(t0 + 5,  pA1.y) STEP(t0 + 6,  pA1.z) STEP(t0 + 7,  pA1.w)
        STEP(t0 + 8,  pA2.x) STEP(t0 + 9,  pA2.y) STEP(t0 + 10, pA2.z) STEP(t0 + 11, pA2.w)
        STEP(t0 + 12, pA3.x) STEP(t0 + 13, pA3.y) STEP(t0 + 14, pA3.z) STEP(t0 + 15, pA3.w)
        LOADCHUNK(pA0, pA1, pA2, pA3, t0 + 32)
        STEP(t0 + 16, pB0.x) STEP(t0 + 17, pB0.y) STEP(t0 + 18, pB0.z) STEP(t0 + 19, pB0.w)
        STEP(t0 + 20, pB1.x) STEP(t0 + 21, pB1.y) STEP(t0 + 22, pB1.z) STEP(t0 + 23, pB1.w)
        STEP(t0 + 24, pB2.x) STEP(t0 + 25, pB2.y) STEP(t0 + 26, pB2.z) STEP(t0 + 27, pB2.w)
        STEP(t0 + 28, pB3.x) STEP(t0 + 29, pB3.y) STEP(t0 + 30, pB3.z) STEP(t0 + 31, pB3.w)
    }
#undef STEP
#undef LOADCHUNK
#undef LD

    // ---- log_norm = logsumexp_j(alpha) ----
    float mm = alpha;
    #pragma unroll
    for (int x = 32; x >= 1; x >>= 1) mm = fmaxf(mm, __shfl_xor(mm, x, 64));
    float e = __expf(alpha - mm);
    #pragma unroll
    for (int x = 32; x >= 1; x >>= 1) e += __shfl_xor(e, x, 64);
    if (j == 0) out[b] = sc - (mm + __logf(e));
}

extern "C" void kernel_launch(void* const* d_in, const int* in_sizes, int n_in,
                              void* d_out, int out_size, void* d_ws, size_t ws_size,
                              hipStream_t stream) {
    const float* inputs = (const float*)d_in[0];
    const float* trans  = (const float*)d_in[1];
    const int*   tags   = (const int*)d_in[2];
    const int*   lens   = (const int*)d_in[3];
    float*       out    = (float*)d_out;

    crf_kernel<<<dim3(BB), dim3(64), 0, stream>>>(inputs, trans, tags, lens, out);
}

// Round 2
// 226.560 us; speedup vs baseline: 1.0636x; 1.0051x over previous
//
#include <hip/hip_runtime.h>

#define BB 512
#define TT 512
#define NN 64

__device__ __forceinline__ float readlane_f(float v, int lane) {
    return __int_as_float(__builtin_amdgcn_readlane(__float_as_int(v), lane));
}

// R2 lesson: passing `const float4* E` (pointer to a local array) into dot64
// defeated SROA -> E lived in SCRATCH (VGPR_Count=56), ~256B/lane reloaded
// every step => ~695 cyc/step. Fix: 16 NAMED float4 registers + macro dot,
// every access compile-time-constant (guide rule #20).

// 4-term FMA group against one named float4: sN accumulators carried.
#define DOTG(g, Ev) \
    s0 = fmaf(readlane_f(p, 4 * (g) + 0), Ev.x, s0); \
    s1 = fmaf(readlane_f(p, 4 * (g) + 1), Ev.y, s1); \
    s2 = fmaf(readlane_f(p, 4 * (g) + 2), Ev.z, s2); \
    s3 = fmaf(readlane_f(p, 4 * (g) + 3), Ev.w, s3);

// Full 64-term dot: s_j = sum_i p[i] * E[i][j]; p broadcast via v_readlane
// (in-register, no LDS, no barrier). 4 independent fma chains hide latency.
#define DOT64(p, sres) { \
    float s0 = readlane_f(p, 0) * E0.x; \
    float s1 = readlane_f(p, 1) * E0.y; \
    float s2 = readlane_f(p, 2) * E0.z; \
    float s3 = readlane_f(p, 3) * E0.w; \
    DOTG(1, E1)  DOTG(2, E2)  DOTG(3, E3) \
    DOTG(4, E4)  DOTG(5, E5)  DOTG(6, E6)  DOTG(7, E7) \
    DOTG(8, E8)  DOTG(9, E9)  DOTG(10, E10) DOTG(11, E11) \
    DOTG(12, E12) DOTG(13, E13) DOTG(14, E14) DOTG(15, E15) \
    sres = (s0 + s1) + (s2 + s3); \
}

// One WAVE per batch. Lane j tracks alpha[j] and holds the full E column j
// (64 named VGPRs) -> per-step cross-lane reduction entirely in-register,
// zero barriers, zero LDS. Emits double-buffered 16 ahead in named regs.
__global__ __launch_bounds__(64, 1) void crf_kernel(
    const float* __restrict__ inputs,   // B*T*N fp32
    const float* __restrict__ trans,    // N*N fp32
    const int*   __restrict__ tags,     // B*T
    const int*   __restrict__ lens,     // B
    float*       __restrict__ out)      // [0,512) ll, [512,4608) trans copy
{
    const int b = blockIdx.x;
    const int j = threadIdx.x;          // 0..63

    // pass-through output: transition_params (4096 floats over first 64 blocks)
    if (b < 64) out[BB + b * 64 + j] = trans[b * 64 + j];

    const int L    = lens[b];
    const int last = (L - 1) > 0 ? (L - 1) : 0;

    const float* inb  = inputs + (size_t)b * TT * NN;
    const int*   tagb = tags + (size_t)b * TT;

    // ---- sequence score: unary (t < L) + binary (t+1 < L), 64 lanes x 8 ----
    float sc = 0.f;
    #pragma unroll
    for (int k = 0; k < 8; ++k) {
        const int t  = k * 64 + j;
        const int tg = tagb[t];
        if (t < L) sc += inb[t * NN + tg];
        if (t + 1 < L) sc += trans[tg * NN + tagb[t + 1]];   // L<=511 => safe
    }
    #pragma unroll
    for (int x = 32; x >= 1; x >>= 1) sc += __shfl_xor(sc, x, 64);

    // ---- E column j: E[i][j] = exp(trans[i][j]), 64 floats in NAMED VGPRs ----
    float4 E0, E1, E2, E3, E4, E5, E6, E7, E8, E9, E10, E11, E12, E13, E14, E15;
#define LDE(Ev, g) \
    Ev.x = __expf(trans[(4 * (g) + 0) * NN + j]); \
    Ev.y = __expf(trans[(4 * (g) + 1) * NN + j]); \
    Ev.z = __expf(trans[(4 * (g) + 2) * NN + j]); \
    Ev.w = __expf(trans[(4 * (g) + 3) * NN + j]);
    LDE(E0, 0)   LDE(E1, 1)   LDE(E2, 2)   LDE(E3, 3)
    LDE(E4, 4)   LDE(E5, 5)   LDE(E6, 6)   LDE(E7, 7)
    LDE(E8, 8)   LDE(E9, 9)   LDE(E10, 10) LDE(E11, 11)
    LDE(E12, 12) LDE(E13, 13) LDE(E14, 14) LDE(E15, 15)
#undef LDE

    float alpha = inb[j];   // t = 0

    // emit double-buffer: chunk A computes while chunk B loads, stride 32.
    float4 pA0, pA1, pA2, pA3, pB0, pB1, pB2, pB3;

#define LD(vec, comp, tt) { const int tc_ = (tt) <= last ? (tt) : last; \
                            vec.comp = inb[tc_ * NN + j]; }
#define LOADCHUNK(v0, v1, v2, v3, base) \
    LD(v0, x, (base) + 0)  LD(v0, y, (base) + 1)  LD(v0, z, (base) + 2)  LD(v0, w, (base) + 3)  \
    LD(v1, x, (base) + 4)  LD(v1, y, (base) + 5)  LD(v1, z, (base) + 6)  LD(v1, w, (base) + 7)  \
    LD(v2, x, (base) + 8)  LD(v2, y, (base) + 9)  LD(v2, z, (base) + 10) LD(v2, w, (base) + 11) \
    LD(v3, x, (base) + 12) LD(v3, y, (base) + 13) LD(v3, z, (base) + 14) LD(v3, w, (base) + 15)

#define STEP(tc_, EM) { \
    const float m = readlane_f(alpha, 0); \
    const float p = __expf(alpha - m); \
    float s; \
    DOT64(p, s) \
    if ((tc_) <= last) alpha = ((EM) + m) + __logf(s); \
}

    LOADCHUNK(pA0, pA1, pA2, pA3, 1)

    for (int t0 = 1; t0 <= last; t0 += 32) {
        LOADCHUNK(pB0, pB1, pB2, pB3, t0 + 16)
        STEP(t0 + 0,  pA0.x) STEP(t0 + 1,  pA0.y) STEP(t0 + 2,  pA0.z) STEP(t0 + 3,  pA0.w)
        STEP(t0 + 4,  pA1.x) STEP(t0 + 5,  pA1.y) STEP(t0 + 6,  pA1.z) STEP(t0 + 7,  pA1.w)
        STEP(t0 + 8,  pA2.x) STEP(t0 + 9,  pA2.y) STEP(t0 + 10, pA2.z) STEP(t0 + 11, pA2.w)
        STEP(t0 + 12, pA3.x) STEP(t0 + 13, pA3.y) STEP(t0 + 14, pA3.z) STEP(t0 + 15, pA3.w)
        LOADCHUNK(pA0, pA1, pA2, pA3, t0 + 32)
        STEP(t0 + 16, pB0.x) STEP(t0 + 17, pB0.y) STEP(t0 + 18, pB0.z) STEP(t0 + 19, pB0.w)
        STEP(t0 + 20, pB1.x) STEP(t0 + 21, pB1.y) STEP(t0 + 22, pB1.z) STEP(t0 + 23, pB1.w)
        STEP(t0 + 24, pB2.x) STEP(t0 + 25, pB2.y) STEP(t0 + 26, pB2.z) STEP(t0 + 27, pB2.w)
        STEP(t0 + 28, pB3.x) STEP(t0 + 29, pB3.y) STEP(t0 + 30, pB3.z) STEP(t0 + 31, pB3.w)
    }
#undef STEP
#undef LOADCHUNK
#undef LD

    // ---- log_norm = logsumexp_j(alpha) ----
    float mm = alpha;
    #pragma unroll
    for (int x = 32; x >= 1; x >>= 1) mm = fmaxf(mm, __shfl_xor(mm, x, 64));
    float e = __expf(alpha - mm);
    #pragma unroll
    for (int x = 32; x >= 1; x >>= 1) e += __shfl_xor(e, x, 64);
    if (j == 0) out[b] = sc - (mm + __logf(e));
}

extern "C" void kernel_launch(void* const* d_in, const int* in_sizes, int n_in,
                              void* d_out, int out_size, void* d_ws, size_t ws_size,
                              hipStream_t stream) {
    const float* inputs = (const float*)d_in[0];
    const float* trans  = (const float*)d_in[1];
    const int*   tags   = (const int*)d_in[2];
    const int*   lens   = (const int*)d_in[3];
    float*       out    = (float*)d_out;

    crf_kernel<<<dim3(BB), dim3(64), 0, stream>>>(inputs, trans, tags, lens, out);
}